// Round 3
// baseline (544.961 us; speedup 1.0000x reference)
//
#include <hip/hip_runtime.h>
#include <stdint.h>

typedef unsigned short u16;
typedef unsigned int u32;
typedef unsigned long long u64;

typedef _Float16 f16x8 __attribute__((ext_vector_type(8)));
typedef __attribute__((ext_vector_type(4))) float f32x4;

// ---------------- workspace layout (bytes) ----------------
#define OFF_SBITS 0u
#define SBITS_BYTES (2048u * 128u * 32u)             // 8 MiB: u64[2048][128][4]
#define OFF_WSWZ (SBITS_BYTES)                       // fp16 2-split, kc-major swizzle:
                                                     // u16 idx = kc*16384 + s*8192 + j*32 + q4*8 + k7
#define WSWZ_BYTES (8u * 32768u)                     // 8 chunks x 32 KB = 256 KiB
#define OFF_CF   (OFF_WSWZ + WSWZ_BYTES)             // float4[256]: W0,W1,W2,K (BN folded)

#define WSCALE 2048.0f
#define INV_WSCALE (1.0f / 2048.0f)

// ---------------- kernel 1: prep (W 2-way fp16 split, DMA-order swizzle) ----
__global__ __launch_bounds__(256) void prep_kernel(
    const float* __restrict__ conv_w, const float* __restrict__ conv_b,
    const float* __restrict__ gamma,  const float* __restrict__ beta,
    const float* __restrict__ mean,   const float* __restrict__ var,
    const float* __restrict__ lin_w,  uint8_t* __restrict__ ws) {
    int tid = threadIdx.x;
    int blk = blockIdx.x;
    if (blk < 256) {
        int j = blk;
        int k = tid;
        float wsc = lin_w[j * 256 + k] * WSCALE;     // exact (x 2^11)
        _Float16 hi = (_Float16)wsc;                 // RN
        float r = wsc - (float)hi;
        _Float16 lo = (_Float16)r;
        union { _Float16 h; u16 u; } ch, cl;
        ch.h = hi; cl.h = lo;
        int kc = k >> 5, q4 = (k >> 3) & 3, k7 = k & 7;
        u16* wsw = (u16*)(ws + OFF_WSWZ);
        size_t base = (size_t)kc * 16384 + (size_t)j * 32 + q4 * 8 + k7;
        wsw[base]         = ch.u;                    // s = 0
        wsw[base + 8192]  = cl.u;                    // s = 1
    } else {
        int h = tid;
        float inv = gamma[h] / sqrtf(var[h] + 1e-5f);
        float K = (conv_b[h] - mean[h]) * inv + beta[h];
        ((float4*)(ws + OFF_CF))[h] = make_float4(conv_w[h * 3 + 0] * inv,
                                                  conv_w[h * 3 + 1] * inv,
                                                  conv_w[h * 3 + 2] * inv, K);
    }
}

// ---------------- kernel 2: encoder (conv+BN+LIF over h, bit-pack spikes) --
// 2 positions/thread (b and b+32). coefs staged to LDS once, broadcast reads.
__global__ __launch_bounds__(256) void encoder_kernel(
    const float* __restrict__ x,
    const float4* __restrict__ cf,
    u64* __restrict__ sbits) {
    __shared__ float4 cfl[256];
    int tid = threadIdx.x;
    cfl[tid] = cf[tid];

    int p = blockIdx.x * 256 + tid;               // 0..131071
    int c = p & 31;
    int l = (p >> 5) & 127;
    int b0 = p >> 12;                             // 0..31
    int xb = b0 * 4096 + l * 32 + c;
    float xb0 = x[xb],            xb1 = x[xb + 131072];
    float xa0 = (l > 0)   ? x[xb - 32]          : 0.f;
    float xa1 = (l > 0)   ? x[xb + 131072 - 32] : 0.f;
    float xc0 = (l < 127) ? x[xb + 32]          : 0.f;
    float xc1 = (l < 127) ? x[xb + 131072 + 32] : 0.f;
    u64* d0 = sbits + ((size_t)(b0 * 32 + c) * 128 + (size_t)l) * 4;
    u64* d1 = d0 + (size_t)1024 * 512;            // n1 = n0 + 1024

    __syncthreads();
    float v0 = 0.f, v1 = 0.f;
    u64 cur0 = 0ull, cur1 = 0ull;
    #pragma unroll 8
    for (int h = 0; h < 256; ++h) {
        float4 a = cfl[h];
        float e0 = fmaf(a.x, xa0, fmaf(a.y, xb0, fmaf(a.z, xc0, a.w)));
        float e1 = fmaf(a.x, xa1, fmaf(a.y, xb1, fmaf(a.z, xc1, a.w)));
        v0 = v0 + (e0 - v0) * 0.5f;
        v1 = v1 + (e1 - v1) * 0.5f;
        bool s0 = (v0 >= 1.0f);
        bool s1 = (v1 >= 1.0f);
        cur0 |= ((u64)(s0 ? 1u : 0u)) << (h & 63);
        cur1 |= ((u64)(s1 ? 1u : 0u)) << (h & 63);
        if ((h & 63) == 63) {
            d0[h >> 6] = cur0; d1[h >> 6] = cur1;
            cur0 = 0ull; cur1 = 0ull;
        }
        v0 = s0 ? 0.f : v0;
        v1 = s1 ? 0.f : v1;
    }
}

// ---------------- kernel 3: GEMM (binary A bits, 2-split fp16 W) + scan ----
// block = sequence n (2048 blocks). tile 128(t) x 256(j), 4 waves x [128x64].
// LDS: [0,6144)        A words: 128 rows x 12 dwords (8 data + 4 pad)
//      [6144,38912)    B chunk: 2 splits x 256 j x 64 B rows (DMA linear order)
// epilogue reuse: Zbuf float[256 j][32 t] = 32768 B
#define AROW 12

__device__ __forceinline__ void gload_lds16(const void* g, void* l) {
    __builtin_amdgcn_global_load_lds(
        (const __attribute__((address_space(1))) u32*)g,
        (__attribute__((address_space(3))) u32*)l, 16, 0, 0);
}

__global__ __launch_bounds__(256, 4) void gemm_scan_kernel(
    const u64* __restrict__ sbits,
    const uint4* __restrict__ wswz,
    const float* __restrict__ lin_b,
    float* __restrict__ out) {
    __shared__ __align__(16) uint8_t smem[38912];
    u32*     Awords = (u32*)smem;
    uint8_t* Blds   = smem + 6144;
    float*   Zbuf   = (float*)smem;

    int tid  = threadIdx.x;
    int n    = blockIdx.x;
    int lane = tid & 63;
    int w    = tid >> 6;
    int l15  = lane & 15;
    int quad = lane >> 4;

    // stage A bits: 4 KB data into 48 B-padded rows (2-way-free b32 reads)
    {
        const uint4* src = (const uint4*)(sbits + (size_t)n * 512);
        uint4 v = src[tid];
        *(uint4*)(Awords + (tid >> 1) * AROW + (tid & 1) * 4) = v;
    }

    f32x4 acc[8][4];
    #pragma unroll
    for (int mf = 0; mf < 8; ++mf)
        #pragma unroll
        for (int nf = 0; nf < 4; ++nf) {
            f32x4 z = {0.f, 0.f, 0.f, 0.f};
            acc[mf][nf] = z;
        }

    for (int kc = 0; kc < 8; ++kc) {
        __syncthreads();                       // prev-kc B reads done
        // DMA B chunk kc (32 KB): 8 x global_load_lds_dwordx4 per thread,
        // LDS base wave-uniform + lane*16 (global layout pre-swizzled to match)
        const uint4* src = wswz + (size_t)kc * 2048;
        #pragma unroll
        for (int ii = 0; ii < 8; ++ii)
            gload_lds16(src + ii * 256 + tid,
                        Blds + (size_t)(ii * 256 + w * 64) * 16);

        // A fragments from bitmask (VALU overlaps DMA flight)
        f16x8 afr[8];
        #pragma unroll
        for (int mf = 0; mf < 8; ++mf) {
            u32 word = Awords[(mf * 16 + l15) * AROW + kc];
            u32 b = (word >> (quad * 8)) & 0xFFu;
            u32 s1 = b | (b << 15);
            union { u32 u[4]; f16x8 v; } cv;
            cv.u[0] = ((s1     ) & 0x00010001u) * 0x3C00u;
            cv.u[1] = ((s1 >> 2) & 0x00010001u) * 0x3C00u;
            cv.u[2] = ((s1 >> 4) & 0x00010001u) * 0x3C00u;
            cv.u[3] = ((s1 >> 6) & 0x00010001u) * 0x3C00u;
            afr[mf] = cv.v;
        }
        __syncthreads();                       // vmcnt(0) drain: DMA visible

        #pragma unroll
        for (int s = 0; s < 2; ++s)
            #pragma unroll
            for (int nf = 0; nf < 4; ++nf) {
                f16x8 bfr = *(const f16x8*)(Blds + s * 16384 +
                                            (w * 64 + nf * 16 + l15) * 64 + quad * 16);
                #pragma unroll
                for (int mf = 0; mf < 8; ++mf)
                    acc[mf][nf] = __builtin_amdgcn_mfma_f32_16x16x32_f16(
                        afr[mf], bfr, acc[mf][nf], 0, 0, 0);
            }
    }

    // ---- epilogue: Zbuf [j][t] b128 round-trip (4 phases) + LIF scan ----
    float bias = lin_b[tid];                   // j = tid
    float v = 0.f, sOut = 0.f;
    for (int ph = 0; ph < 4; ++ph) {
        __syncthreads();
        #pragma unroll
        for (int mm = 0; mm < 2; ++mm) {
            int mf = ph * 2 + mm;
            #pragma unroll
            for (int nf = 0; nf < 4; ++nf) {
                int jj = w * 64 + nf * 16 + l15;
                *(f32x4*)(Zbuf + jj * 32 + mm * 16 + quad * 4) = acc[mf][nf];
            }
        }
        __syncthreads();
        #pragma unroll
        for (int g = 0; g < 8; ++g) {
            f32x4 z4 = *(const f32x4*)(Zbuf + tid * 32 + g * 4);
            #pragma unroll
            for (int r = 0; r < 4; ++r) {
                float z = fmaf(z4[r], INV_WSCALE, bias);
                v = v + (z - v) * 0.5f;
                bool s = (v >= 1.0f);
                if (ph == 3 && g == 7 && r == 3) sOut = s ? 1.f : 0.f;
                v = s ? 0.f : v;
            }
        }
    }
    out[(size_t)n * 256 + tid]           = sOut;   // (64,1,8192) flat
    out[524288u + (size_t)n * 256 + tid] = sOut;   // (64,8192) flat (identical)
}

// ---------------- launcher ----------------
extern "C" void kernel_launch(void* const* d_in, const int* in_sizes, int n_in,
                              void* d_out, int out_size, void* d_ws, size_t ws_size,
                              hipStream_t stream) {
    const float* x      = (const float*)d_in[0];
    const float* conv_w = (const float*)d_in[1];
    const float* conv_b = (const float*)d_in[2];
    const float* gamma  = (const float*)d_in[3];
    const float* beta   = (const float*)d_in[4];
    const float* mean   = (const float*)d_in[5];
    const float* var    = (const float*)d_in[6];
    const float* lin_w  = (const float*)d_in[7];
    const float* lin_b  = (const float*)d_in[8];
    uint8_t* ws = (uint8_t*)d_ws;
    float* out = (float*)d_out;

    hipLaunchKernelGGL(prep_kernel, dim3(257), dim3(256), 0, stream,
                       conv_w, conv_b, gamma, beta, mean, var, lin_w, ws);
    hipLaunchKernelGGL(encoder_kernel, dim3(512), dim3(256), 0, stream,
                       x, (const float4*)(ws + OFF_CF), (u64*)(ws + OFF_SBITS));
    hipLaunchKernelGGL(gemm_scan_kernel, dim3(2048), dim3(256), 0, stream,
                       (const u64*)(ws + OFF_SBITS),
                       (const uint4*)(ws + OFF_WSWZ), lin_b, out);
}

// Round 4
// 166.083 us; speedup vs baseline: 3.2813x; 3.2813x over previous
//
#include <hip/hip_runtime.h>
#include <stdint.h>

typedef unsigned short u16;
typedef unsigned int u32;
typedef unsigned long long u64;

typedef _Float16 f16x8 __attribute__((ext_vector_type(8)));
typedef __attribute__((ext_vector_type(4))) float f32x4;

// ---------------- workspace layout (bytes) ----------------
#define OFF_SBITS 0u
#define SBITS_BYTES (2048u * 128u * 32u)             // 8 MiB: u64[2048][128][4]
#define OFF_WSWZ (SBITS_BYTES)                       // fp16 2-split, kc-major swizzle:
                                                     // u16 idx = kc*16384 + s*8192 + j*32 + q4*8 + k7
#define WSWZ_BYTES (8u * 32768u)                     // 8 chunks x 32 KB = 256 KiB
#define OFF_CF   (OFF_WSWZ + WSWZ_BYTES)             // float4[256]: W0,W1,W2,K (BN folded)

#define WSCALE 2048.0f
#define INV_WSCALE (1.0f / 2048.0f)

// ---------------- kernel 1: prep (W 2-way fp16 split, DMA-order swizzle) ----
__global__ __launch_bounds__(256) void prep_kernel(
    const float* __restrict__ conv_w, const float* __restrict__ conv_b,
    const float* __restrict__ gamma,  const float* __restrict__ beta,
    const float* __restrict__ mean,   const float* __restrict__ var,
    const float* __restrict__ lin_w,  uint8_t* __restrict__ ws) {
    int tid = threadIdx.x;
    int blk = blockIdx.x;
    if (blk < 256) {
        int j = blk;
        int k = tid;
        float wsc = lin_w[j * 256 + k] * WSCALE;     // exact (x 2^11)
        _Float16 hi = (_Float16)wsc;                 // RN
        float r = wsc - (float)hi;
        _Float16 lo = (_Float16)r;
        union { _Float16 h; u16 u; } ch, cl;
        ch.h = hi; cl.h = lo;
        int kc = k >> 5, q4 = (k >> 3) & 3, k7 = k & 7;
        u16* wsw = (u16*)(ws + OFF_WSWZ);
        size_t base = (size_t)kc * 16384 + (size_t)j * 32 + q4 * 8 + k7;
        wsw[base]         = ch.u;                    // s = 0
        wsw[base + 8192]  = cl.u;                    // s = 1
    } else {
        int h = tid;
        float inv = gamma[h] / sqrtf(var[h] + 1e-5f);
        float K = (conv_b[h] - mean[h]) * inv + beta[h];
        ((float4*)(ws + OFF_CF))[h] = make_float4(conv_w[h * 3 + 0] * inv,
                                                  conv_w[h * 3 + 1] * inv,
                                                  conv_w[h * 3 + 2] * inv, K);
    }
}

// ---------------- kernel 2: encoder (conv+BN+LIF over h, bit-pack spikes) --
// 2 positions/thread (b and b+32). coefs staged to LDS once, broadcast reads.
__global__ __launch_bounds__(256) void encoder_kernel(
    const float* __restrict__ x,
    const float4* __restrict__ cf,
    u64* __restrict__ sbits) {
    __shared__ float4 cfl[256];
    int tid = threadIdx.x;
    cfl[tid] = cf[tid];

    int p = blockIdx.x * 256 + tid;               // 0..131071
    int c = p & 31;
    int l = (p >> 5) & 127;
    int b0 = p >> 12;                             // 0..31
    int xb = b0 * 4096 + l * 32 + c;
    float xb0 = x[xb],            xb1 = x[xb + 131072];
    float xa0 = (l > 0)   ? x[xb - 32]          : 0.f;
    float xa1 = (l > 0)   ? x[xb + 131072 - 32] : 0.f;
    float xc0 = (l < 127) ? x[xb + 32]          : 0.f;
    float xc1 = (l < 127) ? x[xb + 131072 + 32] : 0.f;
    u64* d0 = sbits + ((size_t)(b0 * 32 + c) * 128 + (size_t)l) * 4;
    u64* d1 = d0 + (size_t)1024 * 512;            // n1 = n0 + 1024

    __syncthreads();
    float v0 = 0.f, v1 = 0.f;
    u64 cur0 = 0ull, cur1 = 0ull;
    #pragma unroll 8
    for (int h = 0; h < 256; ++h) {
        float4 a = cfl[h];
        float e0 = fmaf(a.x, xa0, fmaf(a.y, xb0, fmaf(a.z, xc0, a.w)));
        float e1 = fmaf(a.x, xa1, fmaf(a.y, xb1, fmaf(a.z, xc1, a.w)));
        v0 = v0 + (e0 - v0) * 0.5f;
        v1 = v1 + (e1 - v1) * 0.5f;
        bool s0 = (v0 >= 1.0f);
        bool s1 = (v1 >= 1.0f);
        cur0 |= ((u64)(s0 ? 1u : 0u)) << (h & 63);
        cur1 |= ((u64)(s1 ? 1u : 0u)) << (h & 63);
        if ((h & 63) == 63) {
            d0[h >> 6] = cur0; d1[h >> 6] = cur1;
            cur0 = 0ull; cur1 = 0ull;
        }
        v0 = s0 ? 0.f : v0;
        v1 = s1 ? 0.f : v1;
    }
}

// ---------------- kernel 3: GEMM (binary A bits, 2-split fp16 W) + scan ----
// block = sequence n (2048 blocks). tile 128(t) x 256(j), 4 waves x [128x64].
// LDS: [0,6144)        A words: 128 rows x 12 dwords (8 data + 4 pad)
//      [6144,38912)    B chunk: 2 splits x 256 j x 64 B rows (DMA linear order)
// epilogue reuse: Zbuf float[32 t][258 j] (conflict-free stride-1 lane reads)
#define AROW 12

__device__ __forceinline__ void gload_lds16(const void* g, void* l) {
    __builtin_amdgcn_global_load_lds(
        (const __attribute__((address_space(1))) u32*)g,
        (__attribute__((address_space(3))) u32*)l, 16, 0, 0);
}

// (256,3): VGPR cap ~170 -> no spill (r3's (256,4) cap=128 spilled acc ->
// 1.7 GB scratch writes). LDS 38912 still allows 4 blocks/CU if VGPR<=128.
__global__ __launch_bounds__(256, 3) void gemm_scan_kernel(
    const u64* __restrict__ sbits,
    const uint4* __restrict__ wswz,
    const float* __restrict__ lin_b,
    float* __restrict__ out) {
    __shared__ __align__(16) uint8_t smem[38912];
    u32*     Awords = (u32*)smem;
    uint8_t* Blds   = smem + 6144;
    float*   Zbuf   = (float*)smem;

    int tid  = threadIdx.x;
    int n    = blockIdx.x;
    int lane = tid & 63;
    int w    = tid >> 6;
    int l15  = lane & 15;
    int quad = lane >> 4;

    float bias = lin_b[tid];                   // hoisted: overlaps K-loop

    // stage A bits: 4 KB data into 48 B-padded rows (2-way-free b32 reads)
    {
        const uint4* src = (const uint4*)(sbits + (size_t)n * 512);
        uint4 v = src[tid];
        *(uint4*)(Awords + (tid >> 1) * AROW + (tid & 1) * 4) = v;
    }

    f32x4 acc[8][4];
    #pragma unroll
    for (int mf = 0; mf < 8; ++mf)
        #pragma unroll
        for (int nf = 0; nf < 4; ++nf) {
            f32x4 z = {0.f, 0.f, 0.f, 0.f};
            acc[mf][nf] = z;
        }

    for (int kc = 0; kc < 8; ++kc) {
        __syncthreads();                       // prev-kc B reads done
        // DMA B chunk kc (32 KB): 8 x global_load_lds_dwordx4 per thread,
        // LDS base wave-uniform + lane*16 (global layout pre-swizzled to match)
        const uint4* src = wswz + (size_t)kc * 2048;
        #pragma unroll
        for (int ii = 0; ii < 8; ++ii)
            gload_lds16(src + ii * 256 + tid,
                        Blds + (size_t)(ii * 256 + w * 64) * 16);

        // A fragments from bitmask (VALU overlaps DMA flight)
        f16x8 afr[8];
        #pragma unroll
        for (int mf = 0; mf < 8; ++mf) {
            u32 word = Awords[(mf * 16 + l15) * AROW + kc];
            u32 b = (word >> (quad * 8)) & 0xFFu;
            u32 s1 = b | (b << 15);
            union { u32 u[4]; f16x8 v; } cv;
            cv.u[0] = ((s1     ) & 0x00010001u) * 0x3C00u;
            cv.u[1] = ((s1 >> 2) & 0x00010001u) * 0x3C00u;
            cv.u[2] = ((s1 >> 4) & 0x00010001u) * 0x3C00u;
            cv.u[3] = ((s1 >> 6) & 0x00010001u) * 0x3C00u;
            afr[mf] = cv.v;
        }
        __syncthreads();                       // vmcnt(0) drain: DMA visible

        #pragma unroll
        for (int s = 0; s < 2; ++s)
            #pragma unroll
            for (int nf = 0; nf < 4; ++nf) {
                f16x8 bfr = *(const f16x8*)(Blds + s * 16384 +
                                            (w * 64 + nf * 16 + l15) * 64 + quad * 16);
                #pragma unroll
                for (int mf = 0; mf < 8; ++mf)
                    acc[mf][nf] = __builtin_amdgcn_mfma_f32_16x16x32_f16(
                        afr[mf], bfr, acc[mf][nf], 0, 0, 0);
            }
    }

    // ---- epilogue: Zbuf [t][j] (32x258) round-trip, fully unrolled ph ----
    // ph MUST be unrolled: dynamic acc[] indexing forces scratch spill (r3).
    float v = 0.f, sOut = 0.f;
    #pragma unroll
    for (int ph = 0; ph < 4; ++ph) {
        __syncthreads();
        #pragma unroll
        for (int mm = 0; mm < 2; ++mm) {
            int mf = ph * 2 + mm;
            #pragma unroll
            for (int nf = 0; nf < 4; ++nf)
                #pragma unroll
                for (int r = 0; r < 4; ++r) {
                    int tl = mm * 16 + quad * 4 + r;           // 0..31
                    int jj = w * 64 + nf * 16 + l15;           // 0..255
                    Zbuf[tl * 258 + jj] = acc[mf][nf][r];
                }
        }
        __syncthreads();
        #pragma unroll
        for (int tl = 0; tl < 32; ++tl) {
            float z = fmaf(Zbuf[tl * 258 + tid], INV_WSCALE, bias);
            v = v + (z - v) * 0.5f;
            bool s = (v >= 1.0f);
            if (ph == 3 && tl == 31) sOut = s ? 1.f : 0.f;
            v = s ? 0.f : v;
        }
    }
    out[(size_t)n * 256 + tid]           = sOut;   // (64,1,8192) flat
    out[524288u + (size_t)n * 256 + tid] = sOut;   // (64,8192) flat (identical)
}

// ---------------- launcher ----------------
extern "C" void kernel_launch(void* const* d_in, const int* in_sizes, int n_in,
                              void* d_out, int out_size, void* d_ws, size_t ws_size,
                              hipStream_t stream) {
    const float* x      = (const float*)d_in[0];
    const float* conv_w = (const float*)d_in[1];
    const float* conv_b = (const float*)d_in[2];
    const float* gamma  = (const float*)d_in[3];
    const float* beta   = (const float*)d_in[4];
    const float* mean   = (const float*)d_in[5];
    const float* var    = (const float*)d_in[6];
    const float* lin_w  = (const float*)d_in[7];
    const float* lin_b  = (const float*)d_in[8];
    uint8_t* ws = (uint8_t*)d_ws;
    float* out = (float*)d_out;

    hipLaunchKernelGGL(prep_kernel, dim3(257), dim3(256), 0, stream,
                       conv_w, conv_b, gamma, beta, mean, var, lin_w, ws);
    hipLaunchKernelGGL(encoder_kernel, dim3(512), dim3(256), 0, stream,
                       x, (const float4*)(ws + OFF_CF), (u64*)(ws + OFF_SBITS));
    hipLaunchKernelGGL(gemm_scan_kernel, dim3(2048), dim3(256), 0, stream,
                       (const u64*)(ws + OFF_SBITS),
                       (const uint4*)(ws + OFF_WSWZ), lin_b, out);
}